// Round 14
// baseline (1023.672 us; speedup 1.0000x reference)
//
#include <hip/hip_runtime.h>
#include <hip/hip_bf16.h>

#define NN 100000   // nodes
#define NE 200000   // edges
#define NG 2500     // graphs
#define FN 16       // node feats
#define FE 8        // edge feats
#define H1C 32
#define H2C 16
#define KH 16       // edge-MLP hidden
#define GB 512      // persistent grid: 2 blocks/CU x 256 CUs (launch_bounds(256,2) guarantees residency)

typedef __attribute__((ext_vector_type(8))) short short8;
typedef __attribute__((ext_vector_type(4))) float f32x4;

__device__ __forceinline__ float bf2f(unsigned int u){
  union { unsigned int i; float f; } v; v.i = (u & 0xffffu) << 16; return v.f;
}
__device__ __forceinline__ unsigned short f2bf(float f){
  union { float f; unsigned int i; } u; u.f = f;
  unsigned int r = u.i + 0x7fffu + ((u.i >> 16) & 1u);   // RNE, finite data
  return (unsigned short)(r >> 16);
}
__device__ __forceinline__ unsigned int pk2(float a, float b){
  return (unsigned int)f2bf(a) | ((unsigned int)f2bf(b) << 16);
}
__device__ __forceinline__ float rdf(const void* p, long i, bool isbf){
  return isbf ? bf2f(((const unsigned short*)p)[i]) : ((const float*)p)[i];
}
__device__ __forceinline__ int lower_bound_i(const int* __restrict__ a, int n, int v){
  int lo = 0, hi = n;
  while(lo < hi){ int mid = (lo + hi) >> 1; if(a[mid] < v) lo = mid + 1; else hi = mid; }
  return lo;
}
__device__ __forceinline__ bool detect_isbf(const void* __restrict__ x){
  const unsigned short* u = (const unsigned short*)x;
  int lane = threadIdx.x & 63;
  float f = bf2f(u[2*lane]);
  float a = fabsf(f);
  bool sane = (f == 0.0f) || (a > 1e-4f && a < 1e4f);
  unsigned long long b = __ballot(sane);
  return __popcll(b) >= 32;
}

// grid barrier, fixed: arrival = one fetch_add; POLL = device-scope atomic LOAD (coherent
// read served by shared L3 -- replicates, no RMW serialization) + s_sleep backoff.
__device__ __forceinline__ void gridbar(int* __restrict__ cnt, int* __restrict__ gen){
  __syncthreads();
  if(threadIdx.x == 0){
    __threadfence();   // release prior writes
    int g = __hip_atomic_load(gen, __ATOMIC_ACQUIRE, __HIP_MEMORY_SCOPE_AGENT);
    if(__hip_atomic_fetch_add(cnt, 1, __ATOMIC_ACQ_REL, __HIP_MEMORY_SCOPE_AGENT) == GB-1){
      __hip_atomic_store(cnt, 0, __ATOMIC_RELEASE, __HIP_MEMORY_SCOPE_AGENT);
      __threadfence();
      __hip_atomic_fetch_add(gen, 1, __ATOMIC_ACQ_REL, __HIP_MEMORY_SCOPE_AGENT);
    } else {
      while(__hip_atomic_load(gen, __ATOMIC_ACQUIRE, __HIP_MEMORY_SCOPE_AGENT) == g)
        __builtin_amdgcn_s_sleep(16);
    }
    __threadfence();   // acquire
  }
  __syncthreads();
}

#define NW 20
struct WArgs { const void* p[NW]; };
enum {
  OW_E1A=0,     OB_E1A=128,   OW_E1B=144,   OB_E1B=8336,  OW_R1=8848,  OB_R1=9360,
  OW_E2A=9392,  OB_E2A=9520,  OW_E2B=9536,  OB_E2B=17728, OW_R2=18240, OB_R2=18752,
  OW_G1=18768,  OB_G1=19024,  OW_G2=19040,  OB_G2=19056,
  OW_L1=19057,  OB_L1=19313,  OW_L2=19321,  OB_L2=19329
};
// P0 block ranges
#define MB_A 76               // wts cvt: 19330
#define MB_B (MB_A + 19)      // wpack1: 4736
#define MB_C (MB_B + 18)      // wpack2: 4416
#define MB_D (MB_C + 391)     // gate+cvt: NN  (total 504 <= GB)
#define CHUNK 196             // scan chunk: 512*196 = 100352 >= NN

// ---- conv unit (round-9-verified math), one 64-edge tile per call ----
template<int IN, int OUT, bool ABF>
__device__ __forceinline__ void conv_unit(int u, int tid,
    const void* __restrict__ nodef, const unsigned int* __restrict__ hpk,
    const int* __restrict__ srcp, const unsigned short* __restrict__ wpack,
    unsigned short* __restrict__ msg)
{
  constexpr int KMF  = ((KH*IN + IN + 31)/32)*32;   // 288 | 544
  constexpr int KP   = KMF + 8;                     // 296 | 552
  constexpr int NT   = OUT/16;                      // 2 | 1
  constexpr int KS   = KMF/32;                      // 9 | 17
  int lane = tid & 63, m = lane & 15, quad = lane >> 4;
  int wid = tid >> 6;
  int ebase = u*64 + wid*16;
  int em = ebase + m;
  int sn = srcp[em];
  int q1 = quad >> 1;
  int xoff = (IN == 16) ? ((quad & 1)*8) : (quad*8);
  float x8[8];
  short8 xb;
  if(ABF){
    uint4 uu4 = *(const uint4*)((const unsigned short*)nodef + (size_t)sn*IN + xoff);
    unsigned int uu[4] = {uu4.x, uu4.y, uu4.z, uu4.w};
    #pragma unroll
    for(int k = 0; k < 4; k++){ x8[2*k] = bf2f(uu[k]); x8[2*k+1] = bf2f(uu[k] >> 16); }
    xb = *(short8*)&uu4;
  } else {
    const float4* xp = (const float4*)((const float*)nodef + (size_t)sn*IN + xoff);
    float4 v0 = xp[0], v1 = xp[1];
    x8[0]=v0.x; x8[1]=v0.y; x8[2]=v0.z; x8[3]=v0.w;
    x8[4]=v1.x; x8[5]=v1.y; x8[6]=v1.z; x8[7]=v1.w;
    unsigned int* xbp = (unsigned int*)&xb;
    #pragma unroll
    for(int k = 0; k < 4; k++) xbp[k] = pk2(x8[2*k], x8[2*k+1]);
  }
  unsigned int hu[8];
  {
    const uint4* hp = (const uint4*)(hpk + (size_t)em*8);
    uint4 u0 = hp[0], u1 = hp[1];
    hu[0]=u0.x; hu[1]=u0.y; hu[2]=u0.z; hu[3]=u0.w;
    hu[4]=u1.x; hu[5]=u1.y; hu[6]=u1.z; hu[7]=u1.w;
  }
  f32x4 acc[NT];
  #pragma unroll
  for(int nt = 0; nt < NT; nt++) acc[nt] = (f32x4){0.f,0.f,0.f,0.f};
  #pragma unroll
  for(int ks = 0; ks < KS; ks++){
    short8 a;
    if(ks < KS-1){
      float hv = (IN == 16) ? bf2f(hu[ks] >> (16*q1))
                            : bf2f(hu[ks >> 1] >> (16*(ks & 1)));
      unsigned int* ap = (unsigned int*)&a;
      #pragma unroll
      for(int k = 0; k < 4; k++) ap[k] = pk2(hv*x8[2*k], hv*x8[2*k+1]);
    } else {
      if(IN == 16) a = (quad < 2) ? xb : (short8){0,0,0,0,0,0,0,0};
      else         a = xb;
    }
    #pragma unroll
    for(int nt = 0; nt < NT; nt++){
      short8 bfr = *(const short8*)(wpack + (size_t)(nt*16 + m)*KP + ks*32 + quad*8);
      acc[nt] = __builtin_amdgcn_mfma_f32_16x16x32_bf16(a, bfr, acc[nt], 0, 0, 0);
    }
  }
  #pragma unroll
  for(int nt = 0; nt < NT; nt++)
    #pragma unroll
    for(int r = 0; r < 4; r++)   // C layout: row=(lane>>4)*4+reg (edge), col=lane&15
      msg[(size_t)(ebase + quad*4 + r)*OUT + nt*16 + m] = f2bf(acc[nt][r]);
}

__global__ void __launch_bounds__(256, 2) mega_kernel(
    const void* __restrict__ xin, const void* __restrict__ efin, WArgs w,
    const int* __restrict__ ei, const int* __restrict__ batch,
    float* __restrict__ wts, unsigned int* __restrict__ wpack1, unsigned int* __restrict__ wpack2,
    float* __restrict__ gate, float* __restrict__ xf,
    int* __restrict__ deg, int* __restrict__ partials, int* __restrict__ bar,
    int* __restrict__ rowptr, int* __restrict__ cursor, int* __restrict__ srcp,
    unsigned int* __restrict__ hpk1, unsigned int* __restrict__ hpk2,
    unsigned short* __restrict__ h1b, unsigned short* __restrict__ msg,
    float* __restrict__ h2, void* __restrict__ out)
{
  __shared__ int   s_i[512];
  __shared__ float s_f[512];
  __shared__ float s_f2[64];
  __shared__ float s_hd[4*48];
  int b = blockIdx.x, tid = threadIdx.x;
  int* cnt = bar; int* gen = bar + 4;
  bool isbf = detect_isbf(xin);

  // ---- P0: segmented setup (blocks 0..503) + grid-stride histogram ----
  if(b < MB_A){
    int i = b*256 + tid;
    if(i < 19330){
      const int sz[NW] = {128,16,8192,512,512,32, 128,16,8192,512,512,16, 256,16,16,1, 256,8,8,1};
      int seg = 0; long base = 0;
      while(i - base >= sz[seg]){ base += sz[seg]; seg++; }
      wts[i] = rdf(w.p[seg], i - base, isbf);
    }
  } else if(b < MB_B){   // wpack1: 32 rows x 148 u32 (KP=296)
    int j = (b - MB_A)*256 + tid;
    if(j < 4736){
      int n = j / 148; int k = (j % 148) * 2;
      float v0 = 0.f, v1 = 0.f;
      if(k < 256)        v0 = rdf(w.p[2], (long)k*32 + n, isbf);
      else if(k < 272)   v0 = rdf(w.p[3], (long)(k-256)*32 + n, isbf);
      if(k+1 < 256)      v1 = rdf(w.p[2], (long)(k+1)*32 + n, isbf);
      else if(k+1 < 272) v1 = rdf(w.p[3], (long)(k+1-256)*32 + n, isbf);
      wpack1[j] = pk2(v0, v1);
    }
  } else if(b < MB_C){   // wpack2: 16 rows x 276 u32 (KP=552)
    int j = (b - MB_B)*256 + tid;
    if(j < 4416){
      int n = j / 276; int k = (j % 276) * 2;
      float v0 = 0.f, v1 = 0.f;
      if(k < 512)        v0 = rdf(w.p[8], (long)k*16 + n, isbf);
      else if(k < 544)   v0 = rdf(w.p[9], (long)(k-512)*16 + n, isbf);
      if(k+1 < 512)      v1 = rdf(w.p[8], (long)(k+1)*16 + n, isbf);
      else if(k+1 < 544) v1 = rdf(w.p[9], (long)(k+1-512)*16 + n, isbf);
      wpack2[j] = pk2(v0, v1);
    }
  } else if(b < MB_D){   // gate MLP + x conversion
    if(tid < FN*FN) s_f[tid] = rdf(w.p[12], tid, isbf);
    if(tid < FN){ s_f2[tid] = rdf(w.p[13], tid, isbf); s_f2[32 + tid] = rdf(w.p[14], tid, isbf); }
    if(tid == 0) s_f2[63] = rdf(w.p[15], 0, isbf);
    __syncthreads();
    int n = (b - MB_C)*256 + tid;
    if(n < NN){
      float xv[FN];
      if(isbf){
        uint4 u0 = ((const uint4*)xin)[2*n], u1 = ((const uint4*)xin)[2*n+1];
        xv[0]=bf2f(u0.x); xv[1]=bf2f(u0.x>>16); xv[2]=bf2f(u0.y); xv[3]=bf2f(u0.y>>16);
        xv[4]=bf2f(u0.z); xv[5]=bf2f(u0.z>>16); xv[6]=bf2f(u0.w); xv[7]=bf2f(u0.w>>16);
        xv[8]=bf2f(u1.x); xv[9]=bf2f(u1.x>>16); xv[10]=bf2f(u1.y); xv[11]=bf2f(u1.y>>16);
        xv[12]=bf2f(u1.z); xv[13]=bf2f(u1.z>>16); xv[14]=bf2f(u1.w); xv[15]=bf2f(u1.w>>16);
      } else {
        #pragma unroll
        for(int q = 0; q < 4; q++){
          float4 v = ((const float4*)xin)[4*n + q];
          xv[q*4+0]=v.x; xv[q*4+1]=v.y; xv[q*4+2]=v.z; xv[q*4+3]=v.w;
        }
      }
      float4* xo = (float4*)(xf + (size_t)n*FN);
      #pragma unroll
      for(int q = 0; q < 4; q++) xo[q] = make_float4(xv[q*4+0], xv[q*4+1], xv[q*4+2], xv[q*4+3]);
      float g = s_f2[63];
      #pragma unroll
      for(int j = 0; j < FN; j++){
        float hj = s_f2[j];
        #pragma unroll
        for(int i = 0; i < FN; i++) hj += xv[i] * s_f[i*FN + j];
        hj = hj > 0.f ? hj : 0.f;
        g += hj * s_f2[32 + j];
      }
      gate[n] = g;
    }
  }
  for(int t = b*256 + tid; t < NE; t += GB*256) atomicAdd(&deg[ei[NE + t]], 1);
  gridbar(cnt, gen);

  // ---- P1a: per-block chunk sums ----
  {
    int base = b*CHUNK;
    int v = (tid < CHUNK && base + tid < NN) ? deg[base + tid] : 0;
    s_i[tid] = v;
    __syncthreads();
    for(int off = 128; off > 0; off >>= 1){
      if(tid < off) s_i[tid] += s_i[tid + off];
      __syncthreads();
    }
    if(tid == 0) partials[b] = s_i[0];
  }
  gridbar(cnt, gen);
  // ---- P1b: block 0 exclusive-scans 512 partials ----
  if(b == 0){
    s_i[tid] = partials[tid]; s_i[tid + 256] = partials[tid + 256];
    __syncthreads();
    for(int off = 1; off < 512; off <<= 1){
      int v0 = (tid >= off) ? s_i[tid - off] : 0;
      int v1 = (tid + 256 >= off) ? s_i[tid + 256 - off] : 0;
      __syncthreads();
      s_i[tid] += v0; s_i[tid + 256] += v1;
      __syncthreads();
    }
    partials[tid]       = (tid == 0) ? 0 : s_i[tid - 1];
    partials[tid + 256] = s_i[tid + 255];
  }
  gridbar(cnt, gen);
  // ---- P1c: local scan + write rowptr/cursor ----
  {
    int base = b*CHUNK;
    int v = (tid < CHUNK && base + tid < NN) ? deg[base + tid] : 0;
    s_i[tid] = v;
    __syncthreads();
    for(int off = 1; off < 256; off <<= 1){
      int t = (tid >= off) ? s_i[tid - off] : 0;
      __syncthreads();
      s_i[tid] += t;
      __syncthreads();
    }
    int excl = partials[b] + s_i[tid] - v;
    if(tid < CHUNK && base + tid < NN){ rowptr[base + tid] = excl; cursor[base + tid] = excl; }
    if(b == 0 && tid == 0) rowptr[NN] = NE;
  }
  gridbar(cnt, gen);

  // ---- P2: fill + both edge-MLPs (CSR-position output) ----
  {
    __syncthreads();
    if(tid < FE*KH){ s_f[tid] = wts[OW_E1A + tid]; s_f[128 + tid] = wts[OW_E2A + tid]; }
    if(tid < KH){ s_f2[tid] = wts[OB_E1A + tid]; s_f2[16 + tid] = wts[OB_E2A + tid]; }
    __syncthreads();
    for(int e = b*256 + tid; e < NE; e += GB*256){
      int pos = atomicAdd(&cursor[ei[NE + e]], 1);
      srcp[pos] = ei[e];
      float ev[FE];
      if(isbf){
        uint4 u = ((const uint4*)efin)[e];
        ev[0]=bf2f(u.x); ev[1]=bf2f(u.x>>16); ev[2]=bf2f(u.y); ev[3]=bf2f(u.y>>16);
        ev[4]=bf2f(u.z); ev[5]=bf2f(u.z>>16); ev[6]=bf2f(u.w); ev[7]=bf2f(u.w>>16);
      } else {
        float4 a = ((const float4*)efin)[2*e], bb = ((const float4*)efin)[2*e+1];
        ev[0]=a.x; ev[1]=a.y; ev[2]=a.z; ev[3]=a.w; ev[4]=bb.x; ev[5]=bb.y; ev[6]=bb.z; ev[7]=bb.w;
      }
      unsigned int o[8];
      #pragma unroll
      for(int d = 0; d < 8; d++){
        float h0 = s_f2[2*d], h1 = s_f2[2*d+1];
        #pragma unroll
        for(int k = 0; k < FE; k++){
          h0 += ev[k] * s_f[k*KH + 2*d];
          h1 += ev[k] * s_f[k*KH + 2*d+1];
        }
        h0 = h0 > 0.f ? h0 : 0.f; h1 = h1 > 0.f ? h1 : 0.f;
        o[d] = pk2(h0, h1);
      }
      uint4* p1 = (uint4*)(hpk1 + (size_t)pos*8);
      p1[0] = make_uint4(o[0],o[1],o[2],o[3]); p1[1] = make_uint4(o[4],o[5],o[6],o[7]);
      #pragma unroll
      for(int d = 0; d < 8; d++){
        float h0 = s_f2[16 + 2*d], h1 = s_f2[16 + 2*d+1];
        #pragma unroll
        for(int k = 0; k < FE; k++){
          h0 += ev[k] * s_f[128 + k*KH + 2*d];
          h1 += ev[k] * s_f[128 + k*KH + 2*d+1];
        }
        h0 = h0 > 0.f ? h0 : 0.f; h1 = h1 > 0.f ? h1 : 0.f;
        o[d] = pk2(h0, h1);
      }
      uint4* p2 = (uint4*)(hpk2 + (size_t)pos*8);
      p2[0] = make_uint4(o[0],o[1],o[2],o[3]); p2[1] = make_uint4(o[4],o[5],o[6],o[7]);
    }
  }
  gridbar(cnt, gen);

  // ---- P3: conv1 ----
  for(int u = b; u < NE/64; u += GB)
    conv_unit<FN, H1C, false>(u, tid, xf, hpk1, srcp, (const unsigned short*)wpack1, msg);
  gridbar(cnt, gen);

  // ---- P4: gather1 -> h1b (bf16); h1b aliases hpk1 (dead) ----
  {
    __syncthreads();
    for(int i = tid; i < FN*H1C; i += 256) s_f[i] = wts[OW_R1 + i];
    if(tid < H1C) s_f2[tid] = wts[OB_R1 + tid];
    __syncthreads();
    for(int u = b; u < NN*8/256; u += GB){
      int g = u*256 + tid;
      int n = g >> 3, q = g & 7;
      if(n < NN){
        float a0 = s_f2[q*4+0], a1 = s_f2[q*4+1], a2 = s_f2[q*4+2], a3 = s_f2[q*4+3];
        int jb = rowptr[n], je = rowptr[n+1];
        for(int j = jb; j < je; j++){
          const unsigned int* mp = (const unsigned int*)(msg + (size_t)j*H1C + q*4);
          unsigned int u0 = mp[0], u1 = mp[1];
          a0 += bf2f(u0); a1 += bf2f(u0 >> 16); a2 += bf2f(u1); a3 += bf2f(u1 >> 16);
        }
        const float* xr = xf + (size_t)n*FN;
        #pragma unroll
        for(int i = 0; i < FN; i++){
          float xi = xr[i];
          a0 += xi*s_f[i*H1C + q*4+0]; a1 += xi*s_f[i*H1C + q*4+1];
          a2 += xi*s_f[i*H1C + q*4+2]; a3 += xi*s_f[i*H1C + q*4+3];
        }
        a0 = a0>0.f?a0:0.f; a1 = a1>0.f?a1:0.f; a2 = a2>0.f?a2:0.f; a3 = a3>0.f?a3:0.f;
        uint2 hb; hb.x = pk2(a0, a1); hb.y = pk2(a2, a3);
        *(uint2*)(h1b + (size_t)n*H1C + q*4) = hb;
      }
    }
  }
  gridbar(cnt, gen);

  // ---- P5: conv2 (msg reused) ----
  for(int u = b; u < NE/64; u += GB)
    conv_unit<H1C, H2C, true>(u, tid, h1b, hpk2, srcp, (const unsigned short*)wpack2, msg);
  gridbar(cnt, gen);

  // ---- P6: gather2 -> h2 (fp32); h2 aliases hpk2 (dead) ----
  {
    __syncthreads();
    for(int i = tid; i < H1C*H2C; i += 256) s_f[i] = wts[OW_R2 + i];
    if(tid < H2C) s_f2[tid] = wts[OB_R2 + tid];
    __syncthreads();
    for(int u = b; u < (NN*4 + 255)/256; u += GB){
      int g = u*256 + tid;
      int n = g >> 2, q = g & 3;
      if(n < NN){
        float a0 = s_f2[q*4+0], a1 = s_f2[q*4+1], a2 = s_f2[q*4+2], a3 = s_f2[q*4+3];
        int jb = rowptr[n], je = rowptr[n+1];
        for(int j = jb; j < je; j++){
          const unsigned int* mp = (const unsigned int*)(msg + (size_t)j*H2C + q*4);
          unsigned int u0 = mp[0], u1 = mp[1];
          a0 += bf2f(u0); a1 += bf2f(u0 >> 16); a2 += bf2f(u1); a3 += bf2f(u1 >> 16);
        }
        const unsigned int* hb = (const unsigned int*)(h1b + (size_t)n*H1C);
        #pragma unroll
        for(int i2 = 0; i2 < H1C/2; i2++){
          unsigned int u2 = hb[i2];
          float x0 = bf2f(u2), x1 = bf2f(u2 >> 16);
          int i = 2*i2;
          a0 += x0*s_f[i*H2C + q*4+0] + x1*s_f[(i+1)*H2C + q*4+0];
          a1 += x0*s_f[i*H2C + q*4+1] + x1*s_f[(i+1)*H2C + q*4+1];
          a2 += x0*s_f[i*H2C + q*4+2] + x1*s_f[(i+1)*H2C + q*4+2];
          a3 += x0*s_f[i*H2C + q*4+3] + x1*s_f[(i+1)*H2C + q*4+3];
        }
        float4 r; r.x = a0>0.f?a0:0.f; r.y = a1>0.f?a1:0.f; r.z = a2>0.f?a2:0.f; r.w = a3>0.f?a3:0.f;
        *(float4*)(h2 + (size_t)n*H2C + q*4) = r;
      }
    }
  }
  gridbar(cnt, gen);

  // ---- P7: head, one wave per graph (wave-synchronous, per-wave LDS slice) ----
  {
    int wid = tid >> 6, lane = tid & 63;
    float* sz = s_hd + wid*48;
    for(int g = b*4 + wid; g < NG; g += GB*4){
      int start = lower_bound_i(batch, NN, g);
      int end   = lower_bound_i(batch, NN, g + 1);
      float m = -1e30f;
      for(int n = start + lane; n < end; n += 64) m = fmaxf(m, gate[n]);
      #pragma unroll
      for(int o = 32; o >= 1; o >>= 1) m = fmaxf(m, __shfl_xor(m, o));
      float s = 0.f;
      float acc[FN];
      #pragma unroll
      for(int f = 0; f < FN; f++) acc[f] = 0.f;
      for(int n = start + lane; n < end; n += 64){
        float a = __expf(gate[n] - m);
        s += a;
        const float4* xp = (const float4*)(xf + (size_t)n * FN);
        #pragma unroll
        for(int q = 0; q < 4; q++){
          float4 v = xp[q];
          acc[q*4+0] += a*v.x; acc[q*4+1] += a*v.y; acc[q*4+2] += a*v.z; acc[q*4+3] += a*v.w;
        }
      }
      #pragma unroll
      for(int o = 32; o >= 1; o >>= 1){
        s += __shfl_xor(s, o);
        #pragma unroll
        for(int f = 0; f < FN; f++) acc[f] += __shfl_xor(acc[f], o);
      }
      if(lane < FN) sz[H2C + lane] = (end > start && s > 0.f) ? acc[lane] / s : 0.f;
      #pragma unroll
      for(int f = 0; f < H2C; f++) acc[f] = 0.f;
      for(int n = start + lane; n < end; n += 64){
        const float4* hp = (const float4*)(h2 + (size_t)n*H2C);
        #pragma unroll
        for(int q = 0; q < 4; q++){
          float4 v = hp[q];
          acc[q*4+0] += v.x; acc[q*4+1] += v.y; acc[q*4+2] += v.z; acc[q*4+3] += v.w;
        }
      }
      #pragma unroll
      for(int o = 32; o >= 1; o >>= 1){
        #pragma unroll
        for(int f = 0; f < H2C; f++) acc[f] += __shfl_xor(acc[f], o);
      }
      float inv = 1.f / fmaxf((float)(end - start), 1.f);
      if(lane < H2C) sz[lane] = acc[lane] * inv;
      if(lane == 0){
        float t1[8];
        #pragma unroll
        for(int j = 0; j < 8; j++){
          float t = wts[OB_L1 + j];
          #pragma unroll
          for(int c = 0; c < H2C + FN; c++) t += sz[c] * wts[OW_L1 + c*8 + j];
          t1[j] = t;
        }
        float o = wts[OB_L2];
        #pragma unroll
        for(int j = 0; j < 8; j++) o += t1[j] * wts[OW_L2 + j];
        if(isbf) ((__hip_bfloat16*)out)[g] = __float2bfloat16(o);
        else     ((float*)out)[g] = o;
      }
    }
  }
}

extern "C" void kernel_launch(void* const* d_in, const int* in_sizes, int n_in,
                              void* d_out, int out_size, void* d_ws, size_t ws_size,
                              hipStream_t stream)
{
  const int* ei    = (const int*)d_in[22];
  const int* batch = (const int*)d_in[23];

  float* ws = (float*)d_ws;
  float* xf     = ws;                          // 1,600,000 f
  float* gate   = xf + 1600000;                //   100,000 f
  float* wts    = gate + 100000;               //    19,360 f
  int*   rowptr = (int*)(wts + 19360);         //   100,016 i
  int*   cursor = rowptr + 100016;             //   100,000 i
  int*   deg    = cursor + 100000;             //   100,000 i  <- memset start
  int*   partials = deg + 100000;              //       512 i
  int*   bar    = partials + 512;              //        16 i  <- memset end
  int*   srcp   = bar + 16;                    //   200,000 i
  unsigned int* wpack1 = (unsigned int*)(srcp + 200000);   // 4,736 u32
  unsigned int* wpack2 = wpack1 + 4736;                    // 4,416 u32
  unsigned short* h1b  = (unsigned short*)(wpack2 + 4416); // 3,200,000 u16
  unsigned int* hpk1   = (unsigned int*)h1b;   // alias: [NE][8] u32, dead before P4 writes h1b
  unsigned short* msg  = h1b + 3200000;        // 6,400,000 u16 (conv1 then conv2)
  float* h2     = (float*)(msg + 6400000);     // 1,600,000 f
  unsigned int* hpk2   = (unsigned int*)h2;    // alias: dead before P6 writes h2
  // total ~35 MB

  WArgs wa;
  for(int i = 0; i < NW; i++) wa.p[i] = d_in[2 + i];

  hipMemsetAsync(deg, 0, (100000 + 512 + 16)*sizeof(int), stream);
  mega_kernel<<<GB, 256, 0, stream>>>(
      d_in[0], d_in[1], wa, ei, batch,
      wts, wpack1, wpack2, gate, xf,
      deg, partials, bar, rowptr, cursor, srcp,
      hpk1, hpk2, h1b, msg, h2, d_out);
}

// Round 15
// 214.438 us; speedup vs baseline: 4.7737x; 4.7737x over previous
//
#include <hip/hip_runtime.h>
#include <hip/hip_bf16.h>

#define NN 100000   // nodes
#define NE 200000   // edges
#define NG 2500     // graphs
#define FN 16       // node feats
#define FE 8        // edge feats
#define H1C 32
#define H2C 16
#define KH 16       // edge-MLP hidden

typedef __attribute__((ext_vector_type(8))) short short8;
typedef __attribute__((ext_vector_type(4))) float f32x4;

__device__ __forceinline__ float bf2f(unsigned int u){
  union { unsigned int i; float f; } v; v.i = (u & 0xffffu) << 16; return v.f;
}
__device__ __forceinline__ unsigned short f2bf(float f){
  union { float f; unsigned int i; } u; u.f = f;
  unsigned int r = u.i + 0x7fffu + ((u.i >> 16) & 1u);   // RNE, finite data
  return (unsigned short)(r >> 16);
}
__device__ __forceinline__ unsigned int pk2(float a, float b){
  return (unsigned int)f2bf(a) | ((unsigned int)f2bf(b) << 16);
}
__device__ __forceinline__ float rdf(const void* p, long i, bool isbf){
  return isbf ? bf2f(((const unsigned short*)p)[i]) : ((const float*)p)[i];
}
__device__ __forceinline__ int lower_bound_i(const int* __restrict__ a, int n, int v){
  int lo = 0, hi = n;
  while(lo < hi){ int mid = (lo + hi) >> 1; if(a[mid] < v) lo = mid + 1; else hi = mid; }
  return lo;
}
// inline dtype detection: wave-ballot over 64 sampled halfwords of x (deterministic,
// wave-uniform, identical decision across all kernels).
__device__ __forceinline__ bool detect_isbf(const void* __restrict__ x){
  const unsigned short* u = (const unsigned short*)x;
  int lane = threadIdx.x & 63;
  float f = bf2f(u[2*lane]);
  float a = fabsf(f);
  bool sane = (f == 0.0f) || (a > 1e-4f && a < 1e4f);
  unsigned long long b = __ballot(sane);
  return __popcll(b) >= 32;
}

#define NW 20
struct WArgs { const void* p[NW]; };
enum {
  OW_E1A=0,     OB_E1A=128,   OW_E1B=144,   OB_E1B=8336,  OW_R1=8848,  OB_R1=9360,
  OW_E2A=9392,  OB_E2A=9520,  OW_E2B=9536,  OB_E2B=17728, OW_R2=18240, OB_R2=18752,
  OW_G1=18768,  OB_G1=19024,  OW_G2=19040,  OB_G2=19056,
  OW_L1=19057,  OB_L1=19313,  OW_L2=19321,  OB_L2=19329
};

// ---- mega setup: wts-cvt | wpack1 | wpack2 | gate+cvt | histo (block-segmented) ----
#define MB_A 76               // wts cvt: 19330 elems
#define MB_B (MB_A + 19)      // wpack1: 4736
#define MB_C (MB_B + 18)      // wpack2: 4416
#define MB_D (MB_C + 391)     // gate_cvt: NN
#define MB_E (MB_D + 782)     // histo: NE
__global__ void __launch_bounds__(256) mega1_kernel(
    const void* __restrict__ xin, const void* __restrict__ efin, WArgs w,
    const int* __restrict__ ei,
    float* __restrict__ wts, unsigned int* __restrict__ wpack1, unsigned int* __restrict__ wpack2,
    float* __restrict__ gate, float* __restrict__ xf, int* __restrict__ deg)
{
  int b = blockIdx.x, tid = threadIdx.x;
  if(b < MB_A){
    bool isbf = detect_isbf(xin);
    int i = b*256 + tid;
    if(i >= 19330) return;
    const int sz[NW] = {128,16,8192,512,512,32, 128,16,8192,512,512,16, 256,16,16,1, 256,8,8,1};
    int seg = 0; long base = 0;
    while(i - base >= sz[seg]){ base += sz[seg]; seg++; }
    wts[i] = rdf(w.p[seg], i - base, isbf);
    return;
  }
  if(b < MB_B){   // wpack1: 32 rows x 148 u32 (KP=296), round-7-verified layout
    bool isbf = detect_isbf(xin);
    int j = (b - MB_A)*256 + tid;
    if(j >= 4736) return;
    int n = j / 148; int k = (j % 148) * 2;
    float v0 = 0.f, v1 = 0.f;
    if(k < 256)        v0 = rdf(w.p[2], (long)k*32 + n, isbf);
    else if(k < 272)   v0 = rdf(w.p[3], (long)(k-256)*32 + n, isbf);
    if(k+1 < 256)      v1 = rdf(w.p[2], (long)(k+1)*32 + n, isbf);
    else if(k+1 < 272) v1 = rdf(w.p[3], (long)(k+1-256)*32 + n, isbf);
    wpack1[j] = pk2(v0, v1);
    return;
  }
  if(b < MB_C){   // wpack2: 16 rows x 276 u32 (KP=552)
    bool isbf = detect_isbf(xin);
    int j = (b - MB_B)*256 + tid;
    if(j >= 4416) return;
    int n = j / 276; int k = (j % 276) * 2;
    float v0 = 0.f, v1 = 0.f;
    if(k < 512)        v0 = rdf(w.p[8], (long)k*16 + n, isbf);
    else if(k < 544)   v0 = rdf(w.p[9], (long)(k-512)*16 + n, isbf);
    if(k+1 < 512)      v1 = rdf(w.p[8], (long)(k+1)*16 + n, isbf);
    else if(k+1 < 544) v1 = rdf(w.p[9], (long)(k+1-512)*16 + n, isbf);
    wpack2[j] = pk2(v0, v1);
    return;
  }
  if(b < MB_D){   // gate MLP + x conversion (one pass over raw x)
    __shared__ float s_w1[FN*FN], s_b1[FN], s_w2[FN], s_b2v[1];
    bool isbf = detect_isbf(xin);
    if(tid < FN*FN) s_w1[tid] = rdf(w.p[12], tid, isbf);
    if(tid < FN){ s_b1[tid] = rdf(w.p[13], tid, isbf); s_w2[tid] = rdf(w.p[14], tid, isbf); }
    if(tid == 0) s_b2v[0] = rdf(w.p[15], 0, isbf);
    __syncthreads();
    int n = (b - MB_C)*256 + tid;
    if(n >= NN) return;
    float xv[FN];
    if(isbf){
      uint4 u0 = ((const uint4*)xin)[2*n], u1 = ((const uint4*)xin)[2*n+1];
      xv[0]=bf2f(u0.x); xv[1]=bf2f(u0.x>>16); xv[2]=bf2f(u0.y); xv[3]=bf2f(u0.y>>16);
      xv[4]=bf2f(u0.z); xv[5]=bf2f(u0.z>>16); xv[6]=bf2f(u0.w); xv[7]=bf2f(u0.w>>16);
      xv[8]=bf2f(u1.x); xv[9]=bf2f(u1.x>>16); xv[10]=bf2f(u1.y); xv[11]=bf2f(u1.y>>16);
      xv[12]=bf2f(u1.z); xv[13]=bf2f(u1.z>>16); xv[14]=bf2f(u1.w); xv[15]=bf2f(u1.w>>16);
    } else {
      #pragma unroll
      for(int q = 0; q < 4; q++){
        float4 v = ((const float4*)xin)[4*n + q];
        xv[q*4+0]=v.x; xv[q*4+1]=v.y; xv[q*4+2]=v.z; xv[q*4+3]=v.w;
      }
    }
    float4* xo = (float4*)(xf + (size_t)n*FN);
    #pragma unroll
    for(int q = 0; q < 4; q++) xo[q] = make_float4(xv[q*4+0], xv[q*4+1], xv[q*4+2], xv[q*4+3]);
    float g = s_b2v[0];
    #pragma unroll
    for(int j = 0; j < FN; j++){
      float hj = s_b1[j];
      #pragma unroll
      for(int i = 0; i < FN; i++) hj += xv[i] * s_w1[i*FN + j];
      hj = hj > 0.f ? hj : 0.f;
      g += hj * s_w2[j];
    }
    gate[n] = g;
    return;
  }
  {   // histogram of edge targets (deg pre-zeroed by memset)
    int e = (b - MB_D)*256 + tid;
    if(e < NE) atomicAdd(&deg[ei[NE + e]], 1);
  }
}

// ---- single-launch exclusive scan: publish aggregate, PARALLEL poll (98 co-resident blocks) ----
#define SCAN_NB 98
__global__ void __launch_bounds__(256) scan_kernel(
    const int* __restrict__ deg, int* __restrict__ rowptr, int* __restrict__ cursor,
    unsigned int* __restrict__ pub)
{
  __shared__ int s_thr[256];
  __shared__ int s_agg[SCAN_NB];
  __shared__ int s_bcast;
  int tid = threadIdx.x, bid = blockIdx.x;
  int base = bid*1024 + tid*4;
  int v0=0, v1=0, v2=0, v3=0;
  if(base + 3 < NN){
    int4 t4 = *(const int4*)(deg + base);
    v0=t4.x; v1=t4.y; v2=t4.z; v3=t4.w;
  } else {
    if(base+0 < NN) v0 = deg[base+0];
    if(base+1 < NN) v1 = deg[base+1];
    if(base+2 < NN) v2 = deg[base+2];
  }
  int e1 = v0, e2 = v0+v1, e3 = v0+v1+v2, tot = v0+v1+v2+v3;
  s_thr[tid] = tot;
  __syncthreads();
  for(int off = 1; off < 256; off <<= 1){
    int t = (tid >= off) ? s_thr[tid-off] : 0;
    __syncthreads();
    s_thr[tid] += t;
    __syncthreads();
  }
  int thr_excl = s_thr[tid] - tot;
  int agg = s_thr[255];
  if(tid == 0) atomicExch(&pub[bid], ((unsigned int)agg << 1) | 1u);   // device-scope publish
  if(tid < SCAN_NB){
    unsigned int v;
    do { v = atomicAdd(&pub[tid], 0u); } while((v & 1u) == 0u);        // parallel poll
    s_agg[tid] = (int)(v >> 1);
  }
  __syncthreads();
  if(tid == 0){
    int acc = 0;
    for(int p = 0; p < bid; p++) acc += s_agg[p];
    s_bcast = acc;
  }
  __syncthreads();
  int ex = s_bcast + thr_excl;
  if(base + 3 < NN){
    int4 r = make_int4(ex, ex+e1, ex+e2, ex+e3);
    *(int4*)(rowptr + base) = r;
    *(int4*)(cursor + base) = r;
  } else {
    if(base+0 < NN){ rowptr[base+0]=ex;    cursor[base+0]=ex;    }
    if(base+1 < NN){ rowptr[base+1]=ex+e1; cursor[base+1]=ex+e1; }
    if(base+2 < NN){ rowptr[base+2]=ex+e2; cursor[base+2]=ex+e2; }
  }
  if(bid == 0 && tid == 0) rowptr[NN] = NE;
}

// ---- fill + edge-MLP fused ----
__global__ void __launch_bounds__(256) fill_edge_kernel(
    const int* __restrict__ ei, int* __restrict__ cursor,
    const void* __restrict__ efin, const float* __restrict__ wts, const void* __restrict__ xin,
    int* __restrict__ srcp, unsigned int* __restrict__ hpk1, unsigned int* __restrict__ hpk2)
{
  __shared__ float s_w1[FE*KH], s_b1[KH], s_w2[FE*KH], s_b2[KH];
  int tid = threadIdx.x;
  if(tid < FE*KH){ s_w1[tid] = wts[OW_E1A + tid]; s_w2[tid] = wts[OW_E2A + tid]; }
  if(tid < KH){ s_b1[tid] = wts[OB_E1A + tid]; s_b2[tid] = wts[OB_E2A + tid]; }
  bool isbf = detect_isbf(xin);
  __syncthreads();
  int e = blockIdx.x*256 + tid;
  if(e >= NE) return;
  int pos = atomicAdd(&cursor[ei[NE + e]], 1);
  srcp[pos] = ei[e];
  float ev[FE];
  if(isbf){
    uint4 u = ((const uint4*)efin)[e];
    ev[0]=bf2f(u.x); ev[1]=bf2f(u.x>>16); ev[2]=bf2f(u.y); ev[3]=bf2f(u.y>>16);
    ev[4]=bf2f(u.z); ev[5]=bf2f(u.z>>16); ev[6]=bf2f(u.w); ev[7]=bf2f(u.w>>16);
  } else {
    float4 a = ((const float4*)efin)[2*e], b = ((const float4*)efin)[2*e+1];
    ev[0]=a.x; ev[1]=a.y; ev[2]=a.z; ev[3]=a.w; ev[4]=b.x; ev[5]=b.y; ev[6]=b.z; ev[7]=b.w;
  }
  unsigned int o[8];
  #pragma unroll
  for(int d = 0; d < 8; d++){
    float h0 = s_b1[2*d], h1 = s_b1[2*d+1];
    #pragma unroll
    for(int k = 0; k < FE; k++){
      h0 += ev[k] * s_w1[k*KH + 2*d];
      h1 += ev[k] * s_w1[k*KH + 2*d+1];
    }
    h0 = h0 > 0.f ? h0 : 0.f; h1 = h1 > 0.f ? h1 : 0.f;
    o[d] = pk2(h0, h1);
  }
  uint4* p1 = (uint4*)(hpk1 + (size_t)pos*8);
  p1[0] = make_uint4(o[0],o[1],o[2],o[3]); p1[1] = make_uint4(o[4],o[5],o[6],o[7]);
  #pragma unroll
  for(int d = 0; d < 8; d++){
    float h0 = s_b2[2*d], h1 = s_b2[2*d+1];
    #pragma unroll
    for(int k = 0; k < FE; k++){
      h0 += ev[k] * s_w2[k*KH + 2*d];
      h1 += ev[k] * s_w2[k*KH + 2*d+1];
    }
    h0 = h0 > 0.f ? h0 : 0.f; h1 = h1 > 0.f ? h1 : 0.f;
    o[d] = pk2(h0, h1);
  }
  uint4* p2 = (uint4*)(hpk2 + (size_t)pos*8);
  p2[0] = make_uint4(o[0],o[1],o[2],o[3]); p2[1] = make_uint4(o[4],o[5],o[6],o[7]);
}

// ---- NNConv message GEMM, register-built A-fragments (round-9-verified math) ----
template<int IN, int OUT, bool ABF>
__global__ void __launch_bounds__(256) conv_mfma_kernel(
    const void* __restrict__ nodef, const unsigned int* __restrict__ hpk,
    const int* __restrict__ srcp, const unsigned short* __restrict__ wpack,
    unsigned short* __restrict__ msg)
{
  constexpr int KMF  = ((KH*IN + IN + 31)/32)*32;   // 288 | 544
  constexpr int KP   = KMF + 8;                     // 296 | 552
  constexpr int NT   = OUT/16;                      // 2 | 1
  constexpr int KS   = KMF/32;                      // 9 | 17
  int tid = threadIdx.x;
  int lane = tid & 63, m = lane & 15, quad = lane >> 4;
  int wid = tid >> 6;
  int ebase = blockIdx.x*64 + wid*16;               // grid = NE/64 exactly
  int em = ebase + m;
  int sn = srcp[em];
  int q1 = quad >> 1;
  int xoff = (IN == 16) ? ((quad & 1)*8) : (quad*8);
  float x8[8];
  short8 xb;
  if(ABF){
    uint4 u = *(const uint4*)((const unsigned short*)nodef + (size_t)sn*IN + xoff);
    unsigned int uu[4] = {u.x, u.y, u.z, u.w};
    #pragma unroll
    for(int k = 0; k < 4; k++){ x8[2*k] = bf2f(uu[k]); x8[2*k+1] = bf2f(uu[k] >> 16); }
    xb = *(short8*)&u;
  } else {
    const float4* xp = (const float4*)((const float*)nodef + (size_t)sn*IN + xoff);
    float4 v0 = xp[0], v1 = xp[1];
    x8[0]=v0.x; x8[1]=v0.y; x8[2]=v0.z; x8[3]=v0.w;
    x8[4]=v1.x; x8[5]=v1.y; x8[6]=v1.z; x8[7]=v1.w;
    unsigned int* xbp = (unsigned int*)&xb;
    #pragma unroll
    for(int k = 0; k < 4; k++) xbp[k] = pk2(x8[2*k], x8[2*k+1]);
  }
  unsigned int hu[8];
  {
    const uint4* hp = (const uint4*)(hpk + (size_t)em*8);
    uint4 u0 = hp[0], u1 = hp[1];
    hu[0]=u0.x; hu[1]=u0.y; hu[2]=u0.z; hu[3]=u0.w;
    hu[4]=u1.x; hu[5]=u1.y; hu[6]=u1.z; hu[7]=u1.w;
  }

  f32x4 acc[NT];
  #pragma unroll
  for(int nt = 0; nt < NT; nt++) acc[nt] = (f32x4){0.f,0.f,0.f,0.f};

  #pragma unroll
  for(int ks = 0; ks < KS; ks++){
    short8 a;
    if(ks < KS-1){
      float hv = (IN == 16) ? bf2f(hu[ks] >> (16*q1))
                            : bf2f(hu[ks >> 1] >> (16*(ks & 1)));
      unsigned int* ap = (unsigned int*)&a;
      #pragma unroll
      for(int k = 0; k < 4; k++) ap[k] = pk2(hv*x8[2*k], hv*x8[2*k+1]);
    } else {
      if(IN == 16) a = (quad < 2) ? xb : (short8){0,0,0,0,0,0,0,0};
      else         a = xb;
    }
    #pragma unroll
    for(int nt = 0; nt < NT; nt++){
      short8 b = *(const short8*)(wpack + (size_t)(nt*16 + m)*KP + ks*32 + quad*8);
      acc[nt] = __builtin_amdgcn_mfma_f32_16x16x32_bf16(a, b, acc[nt], 0, 0, 0);
    }
  }
  #pragma unroll
  for(int nt = 0; nt < NT; nt++)
    #pragma unroll
    for(int r = 0; r < 4; r++)   // C layout: row=(lane>>4)*4+reg (edge), col=lane&15
      msg[(size_t)(ebase + quad*4 + r)*OUT + nt*16 + m] = f2bf(acc[nt][r]);
}

// h1 = relu(x@wr1 + br1 + sum msg rows) -> bf16. 8 threads/node; msg streaming.
__global__ void __launch_bounds__(256) gather1_kernel(
    const float* __restrict__ xf, const unsigned short* __restrict__ msg,
    const int* __restrict__ rowptr,
    const float* __restrict__ wr, const float* __restrict__ br,
    unsigned short* __restrict__ h1b)
{
  __shared__ float s_w[FN*H1C], s_b[H1C];
  for(int i = threadIdx.x; i < FN*H1C; i += 256) s_w[i] = wr[i];
  if(threadIdx.x < H1C) s_b[threadIdx.x] = br[threadIdx.x];
  __syncthreads();
  int g = blockIdx.x*256 + threadIdx.x;
  int n = g >> 3, q = g & 7;
  if(n >= NN) return;
  float a0 = s_b[q*4+0], a1 = s_b[q*4+1], a2 = s_b[q*4+2], a3 = s_b[q*4+3];
  int jb = rowptr[n], je = rowptr[n+1];
  for(int j = jb; j < je; j++){
    const unsigned int* mp = (const unsigned int*)(msg + (size_t)j*H1C + q*4);
    unsigned int u0 = mp[0], u1 = mp[1];
    a0 += bf2f(u0); a1 += bf2f(u0 >> 16); a2 += bf2f(u1); a3 += bf2f(u1 >> 16);
  }
  const float* xr = xf + (size_t)n*FN;
  #pragma unroll
  for(int i = 0; i < FN; i++){
    float xi = xr[i];
    a0 += xi*s_w[i*H1C + q*4+0]; a1 += xi*s_w[i*H1C + q*4+1];
    a2 += xi*s_w[i*H1C + q*4+2]; a3 += xi*s_w[i*H1C + q*4+3];
  }
  a0 = a0>0.f?a0:0.f; a1 = a1>0.f?a1:0.f; a2 = a2>0.f?a2:0.f; a3 = a3>0.f?a3:0.f;
  uint2 hb; hb.x = pk2(a0, a1); hb.y = pk2(a2, a3);
  *(uint2*)(h1b + (size_t)n*H1C + q*4) = hb;
}

// h2 = relu(h1@wr2 + br2 + sum msg2 rows); 4 threads/node; h1 read as bf16
__global__ void __launch_bounds__(256) gather2_kernel(
    const unsigned short* __restrict__ h1b, const unsigned short* __restrict__ msg,
    const int* __restrict__ rowptr,
    const float* __restrict__ wr, const float* __restrict__ br, float* __restrict__ h2)
{
  __shared__ float s_w[H1C*H2C], s_b[H2C];
  for(int i = threadIdx.x; i < H1C*H2C; i += 256) s_w[i] = wr[i];
  if(threadIdx.x < H2C) s_b[threadIdx.x] = br[threadIdx.x];
  __syncthreads();
  int g = blockIdx.x*256 + threadIdx.x;
  int n = g >> 2, q = g & 3;
  if(n >= NN) return;
  float a0 = s_b[q*4+0], a1 = s_b[q*4+1], a2 = s_b[q*4+2], a3 = s_b[q*4+3];
  int jb = rowptr[n], je = rowptr[n+1];
  for(int j = jb; j < je; j++){
    const unsigned int* mp = (const unsigned int*)(msg + (size_t)j*H2C + q*4);
    unsigned int u0 = mp[0], u1 = mp[1];
    a0 += bf2f(u0); a1 += bf2f(u0 >> 16); a2 += bf2f(u1); a3 += bf2f(u1 >> 16);
  }
  const unsigned int* hb = (const unsigned int*)(h1b + (size_t)n*H1C);
  #pragma unroll
  for(int i2 = 0; i2 < H1C/2; i2++){
    unsigned int u = hb[i2];
    float x0 = bf2f(u), x1 = bf2f(u >> 16);
    int i = 2*i2;
    a0 += x0*s_w[i*H2C + q*4+0] + x1*s_w[(i+1)*H2C + q*4+0];
    a1 += x0*s_w[i*H2C + q*4+1] + x1*s_w[(i+1)*H2C + q*4+1];
    a2 += x0*s_w[i*H2C + q*4+2] + x1*s_w[(i+1)*H2C + q*4+2];
    a3 += x0*s_w[i*H2C + q*4+3] + x1*s_w[(i+1)*H2C + q*4+3];
  }
  float4 r; r.x = a0>0.f?a0:0.f; r.y = a1>0.f?a1:0.f; r.z = a2>0.f?a2:0.f; r.w = a3>0.f?a3:0.f;
  *(float4*)(h2 + (size_t)n*H2C + q*4) = r;
}

// one wave per graph: attention pool + mean-pool h2 + head MLP
__global__ void head_kernel(const float* __restrict__ gate, const float* __restrict__ xf,
    const float* __restrict__ h2, const int* __restrict__ batch, const void* __restrict__ xin,
    const float* __restrict__ wl1, const float* __restrict__ bl1,
    const float* __restrict__ wl2, const float* __restrict__ bl2,
    void* __restrict__ out)
{
  __shared__ float sz[H2C + FN];
  int g = blockIdx.x;
  int lane = threadIdx.x;
  bool isbf = detect_isbf(xin);
  int start = lower_bound_i(batch, NN, g);
  int end   = lower_bound_i(batch, NN, g + 1);
  float m = -1e30f;
  for(int n = start + lane; n < end; n += 64) m = fmaxf(m, gate[n]);
  #pragma unroll
  for(int o = 32; o >= 1; o >>= 1) m = fmaxf(m, __shfl_xor(m, o));
  float s = 0.f;
  float acc[FN];
  #pragma unroll
  for(int f = 0; f < FN; f++) acc[f] = 0.f;
  for(int n = start + lane; n < end; n += 64){
    float a = __expf(gate[n] - m);
    s += a;
    const float4* xp = (const float4*)(xf + (size_t)n * FN);
    #pragma unroll
    for(int q = 0; q < 4; q++){
      float4 v = xp[q];
      acc[q*4+0] += a*v.x; acc[q*4+1] += a*v.y; acc[q*4+2] += a*v.z; acc[q*4+3] += a*v.w;
    }
  }
  #pragma unroll
  for(int o = 32; o >= 1; o >>= 1){
    s += __shfl_xor(s, o);
    #pragma unroll
    for(int f = 0; f < FN; f++) acc[f] += __shfl_xor(acc[f], o);
  }
  if(lane < FN) sz[H2C + lane] = (end > start && s > 0.f) ? acc[lane] / s : 0.f;
  #pragma unroll
  for(int f = 0; f < H2C; f++) acc[f] = 0.f;
  for(int n = start + lane; n < end; n += 64){
    const float4* hp = (const float4*)(h2 + (size_t)n*H2C);
    #pragma unroll
    for(int q = 0; q < 4; q++){
      float4 v = hp[q];
      acc[q*4+0] += v.x; acc[q*4+1] += v.y; acc[q*4+2] += v.z; acc[q*4+3] += v.w;
    }
  }
  #pragma unroll
  for(int o = 32; o >= 1; o >>= 1){
    #pragma unroll
    for(int f = 0; f < H2C; f++) acc[f] += __shfl_xor(acc[f], o);
  }
  float inv = 1.f / fmaxf((float)(end - start), 1.f);
  if(lane < H2C) sz[lane] = acc[lane] * inv;
  __syncthreads();
  if(lane == 0){
    float t1[8];
    #pragma unroll
    for(int j = 0; j < 8; j++){
      float t = bl1[j];
      #pragma unroll
      for(int c = 0; c < H2C + FN; c++) t += sz[c] * wl1[c*8 + j];
      t1[j] = t;
    }
    float o = bl2[0];
    #pragma unroll
    for(int j = 0; j < 8; j++) o += t1[j] * wl2[j];
    if(isbf) ((__hip_bfloat16*)out)[g] = __float2bfloat16(o);
    else     ((float*)out)[g] = o;
  }
}

extern "C" void kernel_launch(void* const* d_in, const int* in_sizes, int n_in,
                              void* d_out, int out_size, void* d_ws, size_t ws_size,
                              hipStream_t stream)
{
  const int* ei    = (const int*)d_in[22];
  const int* batch = (const int*)d_in[23];

  float* ws = (float*)d_ws;
  float* xf     = ws;                          // 1,600,000 f
  float* gate   = xf + 1600000;                //   100,000 f
  float* wts    = gate + 100000;               //    19,360 f
  int*   rowptr = (int*)(wts + 19360);         //   100,016 i
  int*   cursor = rowptr + 100016;             //   100,000 i
  int*   deg    = cursor + 100000;             //   100,000 i
  unsigned int* pub = (unsigned int*)(deg + 100000);  // 256 u32 (98 used)
  int*   srcp   = (int*)(pub + 256);           //   200,000 i
  unsigned int* wpack1 = (unsigned int*)(srcp + 200000);   // 4,736 u32
  unsigned int* wpack2 = wpack1 + 4736;                    // 4,416 u32
  unsigned short* h1b  = (unsigned short*)(wpack2 + 4416); // 3,200,000 u16 (6.4 MB)
  unsigned int* hpk1   = (unsigned int*)h1b;   // alias: [NE][8] u32, dead before gather1
  unsigned short* msg1 = h1b + 3200000;        // 6,400,000 u16 (12.8 MB)
  unsigned short* msg2 = msg1;                 // reuse after gather1
  float* h2     = (float*)(msg1 + 6400000);    // 1,600,000 f
  unsigned int* hpk2   = (unsigned int*)h2;    // alias: dead before gather2
  // total ~35 MB

  WArgs wa;
  for(int i = 0; i < NW; i++) wa.p[i] = d_in[2 + i];

  hipMemsetAsync(deg, 0, (100000 + 256)*sizeof(int), stream);   // deg + pub states
  mega1_kernel<<<MB_E, 256, 0, stream>>>(d_in[0], d_in[1], wa, ei, wts, wpack1, wpack2, gate, xf, deg);
  scan_kernel<<<SCAN_NB, 256, 0, stream>>>(deg, rowptr, cursor, pub);
  fill_edge_kernel<<<(NE + 255)/256, 256, 0, stream>>>(ei, cursor, d_in[1], wts, d_in[0], srcp, hpk1, hpk2);

  conv_mfma_kernel<FN, H1C, false><<<NE/64, 256, 0, stream>>>(
      xf, hpk1, srcp, (const unsigned short*)wpack1, msg1);
  gather1_kernel<<<(NN*8 + 255)/256, 256, 0, stream>>>(xf, msg1, rowptr, wts+OW_R1, wts+OB_R1, h1b);

  conv_mfma_kernel<H1C, H2C, true><<<NE/64, 256, 0, stream>>>(
      h1b, hpk2, srcp, (const unsigned short*)wpack2, msg2);
  gather2_kernel<<<(NN*4 + 255)/256, 256, 0, stream>>>(h1b, msg2, rowptr, wts+OW_R2, wts+OB_R2, h2);

  head_kernel<<<NG, 64, 0, stream>>>(gate, xf, h2, batch, d_in[0],
      wts+OW_L1, wts+OB_L1, wts+OW_L2, wts+OB_L2, d_out);
}